// Round 7
// baseline (1890.198 us; speedup 1.0000x reference)
//
#include <hip/hip_runtime.h>

// mRNN: h_{t+1} = h + 0.1*(-h + relu(h) @ W_eff^T + tonic + ext) + 0.01*noise
// out[b,t] = mean of relu(h[500:600]) (out_w is uniform 1/100)
//
// R5 lesson: allocator VGPR budget = "fit 2 blocks/CU": 512thr->128, 1024->64.
// So use 256-thread blocks -> 256 VGPRs/lane. 4 waves, 1 wave/SIMD, 128 WGs.
// Each of the 256 lanes owns COMPLETE target rows (no cross-wave partials):
//   L <100  (S): str row L (4 source blocks) + iti row 600+L (h only)
//   L 100-199 (P): alm row 500+p, snr row 300+p, gpe row 100+p
//   L 200-255 (T): stn rows 200+t & 256+t, thal rows 400+t & 456+t (2nd pair t<44)
// Uniform slot structure {13,13,13(streamed),7+7} = 53 quads; 40 resident
// (160 VGPR), 13 streamed from L2. One raw barrier per step (double-buffered
// r makes the second barrier unnecessary); lgkm-only drain so noise/inp
// prefetch crosses steps. Readout: wave 0, delayed one step, from rbuf.
// R6: fix typedef-vs-local-variable name collision (h2 -> f16x2).

typedef _Float16 f16;
typedef _Float16 f16x2 __attribute__((ext_vector_type(2)));

__device__ __forceinline__ void mac2(unsigned w, unsigned r, float& acc){
#if __has_builtin(__builtin_amdgcn_fdot2)
  acc = __builtin_amdgcn_fdot2(__builtin_bit_cast(f16x2, w), __builtin_bit_cast(f16x2, r), acc, false);
#else
  union U { unsigned u; f16x2 v; } cw, cr;
  cw.u = w; cr.u = r;
  acc += (float)cw.v.x * (float)cr.v.x;
  acc += (float)cw.v.y * (float)cr.v.y;
#endif
}

__device__ __forceinline__ unsigned pack_f16x2(float a, float b){
  union { f16 h[2]; unsigned u; } cv;
  cv.h[0] = (f16)a; cv.h[1] = (f16)b;
  return cv.u;
}

__device__ __forceinline__ void wait_lgkm0(){
  asm volatile("s_waitcnt lgkmcnt(0)" ::: "memory");
}

// ---------------- prep: per-lane slot packing ----------------
// Wp layout: [L=0..255][sq=0..39] resident (sq: 0-12 s1, 13-25 s2, 26-32 s4a,
// 33-39 s4b), then streamed s3 at 10240 + q*256 + L.  Quad q of a sub-slot
// covers source PAIRS (base+4q .. base+4q+3) = source cols 2*(base+4q)..+7,
// clipped to [lo,hi).  All bases are %4==0 so r reads are 16B-aligned.

__device__ __forceinline__ float wval(const float* __restrict__ Wrec,
    const float* __restrict__ Wm, const float* __restrict__ Ws,
    const float* __restrict__ Wf, int i, int j, int lo, int hi){
  if (j < lo || j >= hi) return 0.f;
  int idx = i*700 + j;
  return fmaxf(Wrec[idx], 0.f)*Wm[idx]*Ws[idx] + Wf[idx];
}

__global__ void prep_kernel(const float* __restrict__ Wrec, const float* __restrict__ Wm,
                            const float* __restrict__ Ws, const float* __restrict__ Wf,
                            uint4* __restrict__ Wp){
  int s = blockIdx.x*blockDim.x + threadIdx.x;
  if (s >= 13568) return;
  int L, part, q;        // part: 0=s1 1=s2 2=s4a 3=s4b 4=s3
  if (s < 10240){
    L = s/40; int sq = s - L*40;
    if (sq < 13){ part = 0; q = sq; }
    else if (sq < 26){ part = 1; q = sq-13; }
    else { int q4 = sq-26; if (q4 < 7){ part = 2; q = q4; } else { part = 3; q = q4-7; } }
  } else {
    int s2 = s - 10240; q = s2 >> 8; L = s2 & 255; part = 4;
  }
  int row, base, lo, hi; bool valid = true;
  if (L < 100){                                  // S: str row L (all parts)
    const int bs[5] = {0,200,248,276,300};
    const int ls[5] = {0,400,500,500,600};
    const int hs[5] = {100,500,570,570,700};
    row = L; base = bs[part]; lo = ls[part]; hi = hs[part];
  } else if (L < 200){                           // P
    int p = L-100;
    const int rs[5] = {500,500,300,100,300};
    const int bs[5] = {200,248,0,24,100};
    const int ls[5] = {400,500,0,50,200};
    const int hs[5] = {500,600,50,100,300};
    row = rs[part]+p; base = bs[part]; lo = ls[part]; hi = hs[part];
  } else {                                       // T
    int t = L-200;
    const int rs[5] = {200,400,456,456,256};
    const int bs[5] = {48,148,148,176,48};
    const int ls[5] = {100,300,300,300,100};
    const int hs[5] = {200,400,400,400,200};
    row = rs[part]+t; base = bs[part]; lo = ls[part]; hi = hs[part];
    if (part >= 2 && t >= 44) valid = false;     // 2nd stn/thal rows absent
  }
  unsigned pk[4];
  #pragma unroll
  for (int pq = 0; pq < 4; ++pq){
    int pr = base + q*4 + pq;
    float v0 = 0.f, v1 = 0.f;
    if (valid){
      v0 = wval(Wrec,Wm,Ws,Wf, row, 2*pr,   lo, hi);
      v1 = wval(Wrec,Wm,Ws,Wf, row, 2*pr+1, lo, hi);
    }
    pk[pq] = pack_f16x2(v0, v1);
  }
  Wp[s] = make_uint4(pk[0], pk[1], pk[2], pk[3]);
}

// ---------------- main kernel ----------------
template<int Q>
__device__ __forceinline__ float dot_q(const uint4 (&w)[Q], const uint4* rq){
  float ax = 0.f, ay = 0.f, az = 0.f, aw = 0.f;
  #pragma unroll
  for (int q = 0; q < Q; ++q){
    uint4 r = rq[q];               // LDS read, few distinct addrs per wave
    mac2(w[q].x, r.x, ax);
    mac2(w[q].y, r.y, ay);
    mac2(w[q].z, r.z, az);
    mac2(w[q].w, r.w, aw);
  }
  return (ax + ay) + (az + aw);
}

__global__ __launch_bounds__(256)
void rnn_kernel(const float* __restrict__ inp, const float* __restrict__ noise,
                const float* __restrict__ tonic, const float* __restrict__ outw,
                const uint4* __restrict__ Wp, float* __restrict__ out){
  __shared__ __align__(16) f16 rbuf[2][704];
  const int L = threadIdx.x;            // 0..255 == global lane id
  const int lane = L & 63, wid = L >> 6;
  const int b = blockIdx.x;

  for (int k = L; k < 704; k += 256){ rbuf[0][k] = (f16)0.f; rbuf[1][k] = (f16)0.f; }
  __syncthreads();

  const bool clsS = L < 100, clsP = (L >= 100) && (L < 200), clsT = L >= 200;
  const int p = L - 100, t = L - 200;
  // duty rows
  const int r0 = clsS ? L       : (clsP ? 500+p : 200+t);
  const int r1 = clsS ? 600+L   : (clsP ? 300+p : 400+t);
  const bool v2 = clsP || (clsT && t < 44);
  const bool v3 = clsT && t < 44;
  const int r2 = v2 ? (clsP ? 100+p : 256+t) : 0;
  const int r3 = v3 ? 456+t : 0;
  // r-base pair offsets per sub-slot -> uint4 index (pairs/4)
  const int b1 = (clsS ? 0   : (clsP ? 200 : 48 )) >> 2;
  const int b2 = (clsS ? 200 : (clsP ? 248 : 148)) >> 2;
  const int b3 = (clsS ? 300 : (clsP ? 100 : 48 )) >> 2;
  const int b4a = (clsS ? 248 : (clsP ? 0   : 148)) >> 2;
  const int b4b = (clsS ? 276 : (clsP ? 24  : 176)) >> 2;

  // resident W: 40 quads = 160 VGPR
  uint4 w1[13], w2[13], w4[14];
  #pragma unroll
  for (int q = 0; q < 13; ++q) w1[q] = Wp[L*40 + q];
  #pragma unroll
  for (int q = 0; q < 13; ++q) w2[q] = Wp[L*40 + 13 + q];
  #pragma unroll
  for (int q = 0; q < 14; ++q) w4[q] = Wp[L*40 + 26 + q];
  const uint4* __restrict__ WpS3 = Wp + 10240;

  const float ton0 = tonic[r0];
  const float ton1 = tonic[r1];
  const float ton2 = v2 ? tonic[r2] : 0.f;
  const float ton3 = v3 ? tonic[r3] : 0.f;
  float ow0 = 0.f, ow1 = 0.f;
  if (wid == 0 && lane < 50){ ow0 = outw[2*lane]; ow1 = outw[2*lane+1]; }

  // prefetch externals for t=0
  const size_t nbase = (size_t)b*1000*700;
  float n0 = noise[nbase + r0], n1 = noise[nbase + r1];
  float n2 = v2 ? noise[nbase + r2] : 0.f;
  float n3 = v3 ? noise[nbase + r3] : 0.f;
  float xc = clsS ? inp[(size_t)b*1000*100 + L] : 0.f;

  float h0 = 0.f, h1 = 0.f, h2 = 0.f, h3 = 0.f;

  for (int tt = 0; tt < 1000; ++tt){
    const f16* rc = rbuf[tt & 1];
    f16* rn = rbuf[(tt + 1) & 1];
    const uint4* rc4 = (const uint4*)rc;

    // issue next-step external loads (land during this step; raw barrier
    // never drains vmcnt, so these ride across the barrier)
    const int tn = (tt < 999) ? tt + 1 : 999;
    const size_t nb = ((size_t)b*1000 + tn)*700;
    float n0n = noise[nb + r0], n1n = noise[nb + r1];
    float n2n = v2 ? noise[nb + r2] : 0.f;
    float n3n = v3 ? noise[nb + r3] : 0.f;
    float xn = clsS ? inp[((size_t)b*1000 + tn)*100 + L] : 0.f;

    // issue streamed slot-3 W loads early (L2-resident, coalesced per q)
    uint4 ws3[13];
    #pragma unroll
    for (int q = 0; q < 13; ++q) ws3[q] = WpS3[q*256 + L];

    // readout of out[b,tt-1] from rc (= relu(h_tt)), off the critical path
    if (wid == 0){
      float op = 0.f;
      if (lane < 50){
        unsigned v = ((const unsigned*)(rc + 500))[lane];  // pairs 250+lane
        union { unsigned u; f16x2 h; } cv; cv.u = v;
        op = (float)cv.h.x * ow0 + (float)cv.h.y * ow1;
      }
      #pragma unroll
      for (int d = 32; d > 0; d >>= 1) op += __shfl_xor(op, d);
      if (lane == 0 && tt > 0) out[(size_t)b*1000 + (tt - 1)] = op;
    }

    // ---- phase A: dots ----
    float a1 = dot_q<13>(w1, rc4 + b1);
    float a2 = dot_q<13>(w2, rc4 + b2);
    float a4a, a4b;
    {
      float ax=0.f, ay=0.f;
      #pragma unroll
      for (int q = 0; q < 7; ++q){
        uint4 r = (rc4 + b4a)[q];
        mac2(w4[q].x, r.x, ax); mac2(w4[q].y, r.y, ay);
        mac2(w4[q].z, r.z, ax); mac2(w4[q].w, r.w, ay);
      }
      a4a = ax + ay;
      ax = 0.f; ay = 0.f;
      #pragma unroll
      for (int q = 0; q < 7; ++q){
        uint4 r = (rc4 + b4b)[q];
        mac2(w4[7+q].x, r.x, ax); mac2(w4[7+q].y, r.y, ay);
        mac2(w4[7+q].z, r.z, ax); mac2(w4[7+q].w, r.w, ay);
      }
      a4b = ax + ay;
    }
    float a3;
    {
      float ax=0.f, ay=0.f, az=0.f, aw=0.f;
      #pragma unroll
      for (int q = 0; q < 13; ++q){
        uint4 r = (rc4 + b3)[q];
        mac2(ws3[q].x, r.x, ax); mac2(ws3[q].y, r.y, ay);
        mac2(ws3[q].z, r.z, az); mac2(ws3[q].w, r.w, aw);
      }
      a3 = (ax + ay) + (az + aw);
    }

    // ---- phase B: route accumulators, update h, write r_next ----
    const float a4ab = a4a + a4b;
    const float d0 = clsS ? (a1 + a2 + a3 + a4ab) : (clsP ? a1 + a2 : a1);
    const float d1 = clsS ? 0.f : (clsP ? a3 + a4a : a2);
    const float d2 = clsP ? a4b : a3;
    const float d3 = a4ab;
    const float e1 = clsS ? (xc + 0.01f*n1) : 0.f;

    h0 = h0 + 0.1f*(-h0 + d0 + ton0) + 0.01f*n0;
    h1 = h1 + 0.1f*(-h1 + d1 + ton1 + e1) + 0.01f*n1;
    rn[r0] = (f16)fmaxf(h0, 0.f);
    rn[r1] = (f16)fmaxf(h1, 0.f);
    if (v2){
      h2 = h2 + 0.1f*(-h2 + d2 + ton2) + 0.01f*n2;
      rn[r2] = (f16)fmaxf(h2, 0.f);
    }
    if (v3){
      h3 = h3 + 0.1f*(-h3 + d3 + ton3) + 0.01f*n3;
      rn[r3] = (f16)fmaxf(h3, 0.f);
    }

    n0 = n0n; n1 = n1n; n2 = n2n; n3 = n3n; xc = xn;

    wait_lgkm0();                       // own ds writes retired; NO vmcnt drain
    __builtin_amdgcn_s_barrier();       // r_next visible to all waves
  }

  // final readout: rbuf[0] = relu(h_1000) -> out[b,999]
  if (wid == 0){
    const f16* rc = rbuf[0];
    float op = 0.f;
    if (lane < 50){
      unsigned v = ((const unsigned*)(rc + 500))[lane];
      union { unsigned u; f16x2 h; } cv; cv.u = v;
      op = (float)cv.h.x * ow0 + (float)cv.h.y * ow1;
    }
    #pragma unroll
    for (int d = 32; d > 0; d >>= 1) op += __shfl_xor(op, d);
    if (lane == 0) out[(size_t)b*1000 + 999] = op;
  }
}

extern "C" void kernel_launch(void* const* d_in, const int* in_sizes, int n_in,
                              void* d_out, int out_size, void* d_ws, size_t ws_size,
                              hipStream_t stream){
  const float* inp   = (const float*)d_in[0];
  const float* noise = (const float*)d_in[1];
  const float* Wrec  = (const float*)d_in[2];
  const float* Wmask = (const float*)d_in[3];
  const float* Wsign = (const float*)d_in[4];
  const float* Wfix  = (const float*)d_in[5];
  const float* tonic = (const float*)d_in[6];
  const float* outw  = (const float*)d_in[7];
  float* out = (float*)d_out;
  uint4* Wp = (uint4*)d_ws;    // 13568 quads * 16B = 217 KB packed weights

  prep_kernel<<<53, 256, 0, stream>>>(Wrec, Wmask, Wsign, Wfix, Wp);
  rnn_kernel<<<128, 256, 0, stream>>>(inp, noise, tonic, outw, Wp, out);
}